// Round 10
// baseline (317.468 us; speedup 1.0000x reference)
//
#include <hip/hip_runtime.h>
#include <hip/hip_bf16.h>

typedef __hip_bfloat16 bf16;
typedef __attribute__((ext_vector_type(8))) short bf16x8;
typedef __attribute__((ext_vector_type(4))) float f32x4;

// Problem constants: x (L=1024, N=8, C=1024), H=16 heads, hd=64
#define LOGIT_MAX 4.6051702f   // log(1/0.01)

__device__ __forceinline__ float4 load4(const float* p) { return *(const float4*)p; }

__device__ __forceinline__ void store4bf(bf16* p, float4 v) {
    union { bf16 b[4]; uint2 u; } t;
    t.b[0] = __float2bfloat16(v.x); t.b[1] = __float2bfloat16(v.y);
    t.b[2] = __float2bfloat16(v.z); t.b[3] = __float2bfloat16(v.w);
    *(uint2*)p = t.u;
}

// pack 8 fp32 -> 8 bf16 (RNE, same as __float2bfloat16) as uint4
__device__ __forceinline__ uint4 pack8bf(float4 a, float4 b) {
    union { bf16 h[8]; uint4 u; } t;
    t.h[0] = __float2bfloat16(a.x); t.h[1] = __float2bfloat16(a.y);
    t.h[2] = __float2bfloat16(a.z); t.h[3] = __float2bfloat16(a.w);
    t.h[4] = __float2bfloat16(b.x); t.h[5] = __float2bfloat16(b.y);
    t.h[6] = __float2bfloat16(b.z); t.h[7] = __float2bfloat16(b.w);
    return t.u;
}

// async global->LDS, 16B/lane; lds base wave-uniform, lane i -> base + i*16B
__device__ __forceinline__ void async16(const bf16* g, const bf16* lds) {
    __builtin_amdgcn_global_load_lds(
        (const __attribute__((address_space(1))) void*)g,
        (__attribute__((address_space(3))) void*)lds, 16, 0, 0);
}

// ---------------------------------------------------------------------------
// Kernel 0 (prep + self-detect): every block detects dtype from x's first
// 4096 uint16; block 0 publishes flag + fp32 smallf table; in fp32 mode all
// blocks convert in_proj_weight / out_w to bf16 ws copies (x is converted
// inline inside the qkv GEMM now — no 48 MB round-trip).
// smallf: [0,3072) in_proj_bias, [3072,4096) out_b,
//         [4096,4112) exp(min(ls,MAX)), [4112,4128) head_scale.
// ---------------------------------------------------------------------------
__global__ __launch_bounds__(256) void prep_kernel(
    const void* __restrict__ x, const void* __restrict__ w_in, const void* __restrict__ out_w,
    const void* __restrict__ b_in, const void* __restrict__ out_b,
    const void* __restrict__ ls, const void* __restrict__ hs,
    bf16* __restrict__ wb, bf16* __restrict__ owb,
    float* __restrict__ smallf, int* __restrict__ flag)
{
    __shared__ int cnt_lds[4];
    const unsigned short* xs = (const unsigned short*)x;
    int c = 0;
    for (int i = threadIdx.x; i < 4096; i += 256) {
        const unsigned e = (xs[i] >> 7) & 0xFF;
        if (e >= 0x90) c++;
    }
#pragma unroll
    for (int off = 32; off > 0; off >>= 1) c += __shfl_down(c, off, 64);
    if ((threadIdx.x & 63) == 0) cnt_lds[threadIdx.x >> 6] = c;
    __syncthreads();
    const int f = (cnt_lds[0] + cnt_lds[1] + cnt_lds[2] + cnt_lds[3] > 64) ? 1 : 0;

    if (blockIdx.x == 0) {
        if (threadIdx.x == 0) *flag = f;
        for (int idx = threadIdx.x; idx < 4128; idx += 256) {
            float v;
            if (f) {
                if (idx < 3072)      v = ((const float*)b_in)[idx];
                else if (idx < 4096) v = ((const float*)out_b)[idx - 3072];
                else if (idx < 4112) v = expf(fminf(((const float*)ls)[idx - 4096], LOGIT_MAX));
                else                 v = ((const float*)hs)[idx - 4112];
            } else {
                if (idx < 3072)      v = __bfloat162float(((const bf16*)b_in)[idx]);
                else if (idx < 4096) v = __bfloat162float(((const bf16*)out_b)[idx - 3072]);
                else if (idx < 4112) v = expf(fminf(__bfloat162float(((const bf16*)ls)[idx - 4096]), LOGIT_MAX));
                else                 v = __bfloat162float(((const bf16*)hs)[idx - 4112]);
            }
            smallf[idx] = v;
        }
    }
    if (f != 1) return;
    const size_t NW = 3145728, NO = 1048576;
    const size_t t0   = ((size_t)blockIdx.x * 256 + threadIdx.x) * 4;
    const size_t step = (size_t)gridDim.x * 256 * 4;
    for (size_t i = t0; i < NW; i += step) store4bf(wb + i, load4((const float*)w_in + i));
    for (size_t i = t0; i < NO; i += step) store4bf(owb + i, load4((const float*)out_w + i));
}

// ---------------------------------------------------------------------------
// Kernel 1: MFMA QKV projection, BK=64, fused q/k L2-normalize.
// A (x) staging is dtype-branched: bf16 -> global_load_lds; fp32 -> inline
// fp32 loads + RNE pack + ds_write_b128 to the SAME swizzled layout (the
// conversion rides qkv's idle VALU; kills prep's 48 MB x round-trip).
// ---------------------------------------------------------------------------
__global__ __launch_bounds__(256, 3) void qkv_gemm_mfma_kernel(
    const int* __restrict__ flag,
    const float* __restrict__ Xf, const bf16* __restrict__ Xdir,
    const bf16* __restrict__ Wws, const bf16* __restrict__ Wdir,
    const float* __restrict__ bias_f,
    bf16* __restrict__ q, bf16* __restrict__ k, bf16* __restrict__ vt)
{
    const int f = *flag;
    const bf16* W = f ? Wws : Wdir;
    __shared__ bf16 A_lds[128 * 64];
    __shared__ bf16 B_lds[128 * 64];
    const int tid  = threadIdx.x;
    const int w    = tid >> 6;
    const int lane = tid & 63;
    const int l16  = lane & 15, quad = lane >> 4;
    const int wm   = w >> 1, wn = w & 1;
    const int row0 = blockIdx.y * 128;
    const int col0 = blockIdx.x * 128;
    const int sr   = lane >> 3, sc = lane & 7;
    const int scg  = sc ^ sr;            // source chunk for swizzled staging

    f32x4 acc[4][4] = {};

    for (int kt = 0; kt < 1024; kt += 64) {
        __syncthreads();
        if (f) {
            // fp32 A: load + convert + ds_write (same swizzled layout)
#pragma unroll
            for (int i = 0; i < 4; i++) {
                const int row = w * 32 + i * 8 + sr;
                const float* gp = Xf + (size_t)(row0 + row) * 1024 + kt + scg * 8;
                const float4 a0 = load4(gp), a1 = load4(gp + 4);
                *(uint4*)&A_lds[row * 64 + sc * 8] = pack8bf(a0, a1);
            }
        } else {
#pragma unroll
            for (int i = 0; i < 4; i++) {
                const int br = w * 32 + i * 8;
                async16(Xdir + (size_t)(row0 + br + sr) * 1024 + kt + scg * 8, &A_lds[br * 64]);
            }
        }
#pragma unroll
        for (int i = 0; i < 4; i++) {
            const int br = w * 32 + i * 8;
            async16(W + (size_t)(col0 + br + sr) * 1024 + kt + scg * 8, &B_lds[br * 64]);
        }
        __syncthreads();

#pragma unroll
        for (int kh = 0; kh < 2; kh++) {
            bf16x8 af[4], bf[4];
#pragma unroll
            for (int mt = 0; mt < 4; mt++) {
                const int row = wm * 64 + mt * 16 + l16;
                af[mt] = *(const bf16x8*)&A_lds[row * 64 + (((quad + kh * 4) ^ (row & 7)) * 8)];
            }
#pragma unroll
            for (int nt = 0; nt < 4; nt++) {
                const int row = wn * 64 + nt * 16 + l16;
                bf[nt] = *(const bf16x8*)&B_lds[row * 64 + (((quad + kh * 4) ^ (row & 7)) * 8)];
            }
#pragma unroll
            for (int mt = 0; mt < 4; mt++)
#pragma unroll
                for (int nt = 0; nt < 4; nt++)
                    acc[mt][nt] = __builtin_amdgcn_mfma_f32_16x16x32_bf16(af[mt], bf[nt], acc[mt][nt], 0, 0, 0);
        }
    }

    const int cbase = col0 + wn * 64;          // wave-uniform
    const int part  = cbase >> 10;
    const int h     = (cbase & 1023) >> 6;
    float bias[4];
#pragma unroll
    for (int nt = 0; nt < 4; nt++) bias[nt] = bias_f[cbase + nt * 16 + l16];

    if (part < 2) {
        bf16* dst0 = (part == 0) ? q : k;
#pragma unroll
        for (int mt = 0; mt < 4; mt++) {
#pragma unroll
            for (int rg = 0; rg < 4; rg++) {
                const int r = row0 + wm * 64 + mt * 16 + quad * 4 + rg;
                const int l = r >> 3, nn = r & 7;
                float val[4]; float ss = 0.f;
#pragma unroll
                for (int nt = 0; nt < 4; nt++) {
                    val[nt] = acc[mt][nt][rg] + bias[nt];
                    ss += val[nt] * val[nt];
                }
                ss += __shfl_xor(ss, 1); ss += __shfl_xor(ss, 2);
                ss += __shfl_xor(ss, 4); ss += __shfl_xor(ss, 8);
                const float inv = 1.f / fmaxf(sqrtf(ss), 1e-12f);
                bf16* dp = dst0 + ((size_t)((nn * 16 + h) * 1024 + l)) * 64;
#pragma unroll
                for (int nt = 0; nt < 4; nt++)
                    dp[nt * 16 + l16] = __float2bfloat16(val[nt] * inv);
            }
        }
    } else {
#pragma unroll
        for (int mt = 0; mt < 4; mt++) {
#pragma unroll
            for (int rg = 0; rg < 4; rg++) {
                const int r = row0 + wm * 64 + mt * 16 + quad * 4 + rg;
                const int l = r >> 3, nn = r & 7;
#pragma unroll
                for (int nt = 0; nt < 4; nt++) {
                    const int d = nt * 16 + l16;
                    vt[((size_t)((nn * 16 + h) * 64 + d)) * 1024 + l] =
                        __float2bfloat16(acc[mt][nt][rg] + bias[nt]);
                }
            }
        }
    }
}

// ---------------------------------------------------------------------------
// Kernel 3: MFMA flash attention v2 + XCD swizzle (unchanged).
// ---------------------------------------------------------------------------
__global__ __launch_bounds__(256, 4) void attn_mfma_kernel(
    const bf16* __restrict__ q, const bf16* __restrict__ k,
    const bf16* __restrict__ vt, const float* __restrict__ scale_f,
    bf16* __restrict__ o)
{
    __shared__ bf16 K_lds[64][64];
    __shared__ bf16 Vt_lds[64][64];
    __shared__ bf16 P_lds[4][32][72];
    __shared__ float l_lds[4][32];

    const int bid  = blockIdx.x;
    const int qt   = bid >> 7;         // 0..7  (slow index)
    const int nh   = bid & 127;        // fast index -> XCD = nh & 7
    const int h    = nh & 15;
    const int n    = nh >> 4;
    const int tid  = threadIdx.x;
    const int w    = tid >> 6;
    const int lane = tid & 63;
    const int l16  = lane & 15;
    const int quad = lane >> 4;

    const size_t base = (size_t)nh * (1024 * 64);
    const float ls   = scale_f[4096 + h];
    const float hs   = scale_f[4112 + h];
    const float lsl2 = ls * 1.4426950408889634f;

    bf16x8 qf[2][2];
#pragma unroll
    for (int u = 0; u < 2; u++) {
        const int qrow = qt * 128 + w * 32 + u * 16 + l16;
        const bf16* qp = q + base + (size_t)qrow * 64 + quad * 8;
        qf[u][0] = *(const bf16x8*)qp;
        qf[u][1] = *(const bf16x8*)(qp + 32);
    }

    f32x4 o_acc[2][4] = {};
    float l_part[2] = {0.f, 0.f};

    const int sr = lane >> 3;
    const int sc = lane & 7;

    for (int j0 = 0; j0 < 1024; j0 += 64) {
        __syncthreads();
#pragma unroll
        for (int half = 0; half < 2; half++) {
            const int br  = w * 16 + half * 8;
            const int row = br + sr;
            const int cg  = sc ^ (row & 7);
            async16(k  + base + (size_t)(j0 + row) * 64 + cg * 8, &K_lds[br][0]);
            async16(vt + base + (size_t)row * 1024 + j0 + cg * 8, &Vt_lds[br][0]);
        }
        __syncthreads();

        f32x4 s8[2][4];
#pragma unroll
        for (int s = 0; s < 4; s++) {
            const int krow = s * 16 + l16;
            const int swz  = krow & 7;
            const bf16x8 kf0 = *(const bf16x8*)&K_lds[krow][(quad ^ swz) * 8];
            const bf16x8 kf1 = *(const bf16x8*)&K_lds[krow][((quad + 4) ^ swz) * 8];
#pragma unroll
            for (int u = 0; u < 2; u++) {
                f32x4 a = {};
                a = __builtin_amdgcn_mfma_f32_16x16x32_bf16(kf0, qf[u][0], a, 0, 0, 0);
                a = __builtin_amdgcn_mfma_f32_16x16x32_bf16(kf1, qf[u][1], a, 0, 0, 0);
                s8[u][s] = a;
            }
        }

#pragma unroll
        for (int u = 0; u < 2; u++) {
#pragma unroll
            for (int s = 0; s < 4; s++) {
                union { bf16 b[4]; uint2 uu; } pk;
                float sum = 0.f;
#pragma unroll
                for (int r = 0; r < 4; r++) {
                    const float p = exp2f(fmaf(s8[u][s][r], lsl2, -lsl2));
                    pk.b[r] = __float2bfloat16(p);
                    sum += p;
                }
                l_part[u] += sum;
                *(uint2*)&P_lds[w][u * 16 + l16][s * 16 + quad * 4] = pk.uu;
            }
        }

        bf16x8 pf[2][2];
#pragma unroll
        for (int u = 0; u < 2; u++) {
            pf[u][0] = *(const bf16x8*)&P_lds[w][u * 16 + l16][quad * 8];
            pf[u][1] = *(const bf16x8*)&P_lds[w][u * 16 + l16][32 + quad * 8];
        }
#pragma unroll
        for (int ds = 0; ds < 4; ds++) {
            const int vrow = ds * 16 + l16;
            const int swz  = vrow & 7;
            const bf16x8 vf0 = *(const bf16x8*)&Vt_lds[vrow][(quad ^ swz) * 8];
            const bf16x8 vf1 = *(const bf16x8*)&Vt_lds[vrow][((quad + 4) ^ swz) * 8];
#pragma unroll
            for (int u = 0; u < 2; u++) {
                o_acc[u][ds] = __builtin_amdgcn_mfma_f32_16x16x32_bf16(pf[u][0], vf0, o_acc[u][ds], 0, 0, 0);
                o_acc[u][ds] = __builtin_amdgcn_mfma_f32_16x16x32_bf16(pf[u][1], vf1, o_acc[u][ds], 0, 0, 0);
            }
        }
    }

#pragma unroll
    for (int u = 0; u < 2; u++) {
        float v = l_part[u];
        v += __shfl_xor(v, 16);
        v += __shfl_xor(v, 32);
        l_lds[w][u * 16 + l16] = v;
    }

#pragma unroll
    for (int u = 0; u < 2; u++) {
#pragma unroll
        for (int r = 0; r < 4; r++) {
            const float inv = hs / l_lds[w][u * 16 + quad * 4 + r];
            const int row_l = qt * 128 + w * 32 + u * 16 + quad * 4 + r;
            bf16* dst = o + ((size_t)row_l * 8 + n) * 1024 + h * 64 + l16;
#pragma unroll
            for (int ds = 0; ds < 4; ds++)
                dst[ds * 16] = __float2bfloat16(o_acc[u][ds][r] * inv);
        }
    }
}

// ---------------------------------------------------------------------------
// Kernel 4: MFMA out projection, BK=64, single launch (runtime output dtype).
// ---------------------------------------------------------------------------
__global__ __launch_bounds__(256, 4) void out_gemm_mfma_kernel(
    const int* __restrict__ flag,
    const bf16* __restrict__ A,
    const bf16* __restrict__ Bws, const bf16* __restrict__ Bdir,
    const float* __restrict__ bias_f,
    float* __restrict__ outf, bf16* __restrict__ outb)
{
    const int f = *flag;
    const bf16* B = f ? Bws : Bdir;
    __shared__ bf16 A_lds[128 * 64];
    __shared__ bf16 B_lds[128 * 64];
    const int tid  = threadIdx.x;
    const int w    = tid >> 6;
    const int lane = tid & 63;
    const int l16  = lane & 15, quad = lane >> 4;
    const int wm   = w >> 1, wn = w & 1;
    const int row0 = blockIdx.y * 128;
    const int col0 = blockIdx.x * 128;
    const int sr   = lane >> 3, sc = lane & 7;
    const int scg  = sc ^ sr;

    f32x4 acc[4][4] = {};

    for (int kt = 0; kt < 1024; kt += 64) {
        __syncthreads();
#pragma unroll
        for (int i = 0; i < 4; i++) {
            const int br = w * 32 + i * 8;
            async16(A + (size_t)(row0 + br + sr) * 1024 + kt + scg * 8, &A_lds[br * 64]);
            async16(B + (size_t)(col0 + br + sr) * 1024 + kt + scg * 8, &B_lds[br * 64]);
        }
        __syncthreads();

#pragma unroll
        for (int kh = 0; kh < 2; kh++) {
            bf16x8 af[4], bf[4];
#pragma unroll
            for (int mt = 0; mt < 4; mt++) {
                const int row = wm * 64 + mt * 16 + l16;
                af[mt] = *(const bf16x8*)&A_lds[row * 64 + (((quad + kh * 4) ^ (row & 7)) * 8)];
            }
#pragma unroll
            for (int nt = 0; nt < 4; nt++) {
                const int row = wn * 64 + nt * 16 + l16;
                bf[nt] = *(const bf16x8*)&B_lds[row * 64 + (((quad + kh * 4) ^ (row & 7)) * 8)];
            }
#pragma unroll
            for (int mt = 0; mt < 4; mt++)
#pragma unroll
                for (int nt = 0; nt < 4; nt++)
                    acc[mt][nt] = __builtin_amdgcn_mfma_f32_16x16x32_bf16(af[mt], bf[nt], acc[mt][nt], 0, 0, 0);
        }
    }

#pragma unroll
    for (int mt = 0; mt < 4; mt++) {
        const int rbase = row0 + wm * 64 + mt * 16 + quad * 4;
#pragma unroll
        for (int nt = 0; nt < 4; nt++) {
            const int c = col0 + wn * 64 + nt * 16 + l16;
            const float bias = bias_f[c];
#pragma unroll
            for (int rg = 0; rg < 4; rg++) {
                const float v = acc[mt][nt][rg] + bias;
                const size_t idx = (size_t)(rbase + rg) * 1024 + c;
                if (f) outf[idx] = v; else outb[idx] = __float2bfloat16(v);
            }
        }
    }
}

// ---------------------------------------------------------------------------
extern "C" void kernel_launch(void* const* d_in, const int* in_sizes, int n_in,
                              void* d_out, int out_size, void* d_ws, size_t ws_size,
                              hipStream_t stream)
{
    const size_t SEG = (size_t)8 * 16 * 1024 * 64;   // 8388608 elems
    bf16* qn  = (bf16*)d_ws;
    bf16* kn  = qn + SEG;
    bf16* vt  = kn + SEG;
    bf16* ow  = vt + SEG;
    bf16* wb  = ow + SEG;                  // bf16 copy of in_proj_weight (fp32 mode)
    bf16* owb = wb + 3145728;              // bf16 copy of out_w
    float* smallf = (float*)(owb + 1048576);   // 4128 floats
    int*   flag   = (int*)(smallf + 4128);

    // 0) prep (self-detecting dtype; flag + smallf; weight bf16 copies only)
    prep_kernel<<<512, 256, 0, stream>>>(
        d_in[0], d_in[1], d_in[5], d_in[2], d_in[6], d_in[3], d_in[4],
        wb, owb, smallf, flag);

    // 1) qkv projection (MFMA, BK=64) + fused q/k L2-normalize;
    //    x converted inline during A-staging in fp32 mode
    qkv_gemm_mfma_kernel<<<dim3(3072 / 128, 8192 / 128), 256, 0, stream>>>(
        flag, (const float*)d_in[0], (const bf16*)d_in[0],
        wb, (const bf16*)d_in[1], smallf, qn, kn, vt);

    // 2) flash attention v2 (MFMA, fixed-max softmax, XCD-local nh)
    attn_mfma_kernel<<<dim3(128 * 8), 256, 0, stream>>>(qn, kn, vt, smallf, ow);

    // 3) out projection (MFMA, BK=64), single launch
    out_gemm_mfma_kernel<<<dim3(1024 / 128, 8192 / 128), 256, 0, stream>>>(
        flag, ow, owb, (const bf16*)d_in[5], smallf + 3072,
        (float*)d_out, (bf16*)d_out);
}

// Round 11
// 280.485 us; speedup vs baseline: 1.1319x; 1.1319x over previous
//
#include <hip/hip_runtime.h>
#include <hip/hip_bf16.h>

typedef __hip_bfloat16 bf16;
typedef __attribute__((ext_vector_type(8))) short bf16x8;
typedef __attribute__((ext_vector_type(4))) float f32x4;

// Problem constants: x (L=1024, N=8, C=1024), H=16 heads, hd=64
#define LOGIT_MAX 4.6051702f   // log(1/0.01)

__device__ __forceinline__ float4 load4(const float* p) { return *(const float4*)p; }

__device__ __forceinline__ void store4bf(bf16* p, float4 v) {
    union { bf16 b[4]; uint2 u; } t;
    t.b[0] = __float2bfloat16(v.x); t.b[1] = __float2bfloat16(v.y);
    t.b[2] = __float2bfloat16(v.z); t.b[3] = __float2bfloat16(v.w);
    *(uint2*)p = t.u;
}

// async global->LDS, 16B/lane; lds base wave-uniform, lane i -> base + i*16B
__device__ __forceinline__ void async16(const bf16* g, const bf16* lds) {
    __builtin_amdgcn_global_load_lds(
        (const __attribute__((address_space(1))) void*)g,
        (__attribute__((address_space(3))) void*)lds, 16, 0, 0);
}

// ---------------------------------------------------------------------------
// Kernel 0 (prep + self-detect): every block detects dtype from x's first
// 4096 uint16; block 0 publishes flag + fp32 smallf table; in fp32 mode all
// blocks convert x / in_proj_weight / out_w to bf16 ws copies.
// (R10 lesson: inline conversion inside the GEMM regresses — the prep
// round-trip through HBM is cheaper than a VGPR-path staging loop.)
// smallf: [0,3072) in_proj_bias, [3072,4096) out_b,
//         [4096,4112) exp(min(ls,MAX)), [4112,4128) head_scale.
// ---------------------------------------------------------------------------
__global__ __launch_bounds__(256) void prep_kernel(
    const void* __restrict__ x, const void* __restrict__ w_in, const void* __restrict__ out_w,
    const void* __restrict__ b_in, const void* __restrict__ out_b,
    const void* __restrict__ ls, const void* __restrict__ hs,
    bf16* __restrict__ xb, bf16* __restrict__ wb, bf16* __restrict__ owb,
    float* __restrict__ smallf, int* __restrict__ flag)
{
    __shared__ int cnt_lds[4];
    const unsigned short* xs = (const unsigned short*)x;
    int c = 0;
    for (int i = threadIdx.x; i < 4096; i += 256) {
        const unsigned e = (xs[i] >> 7) & 0xFF;
        if (e >= 0x90) c++;
    }
#pragma unroll
    for (int off = 32; off > 0; off >>= 1) c += __shfl_down(c, off, 64);
    if ((threadIdx.x & 63) == 0) cnt_lds[threadIdx.x >> 6] = c;
    __syncthreads();
    const int f = (cnt_lds[0] + cnt_lds[1] + cnt_lds[2] + cnt_lds[3] > 64) ? 1 : 0;

    if (blockIdx.x == 0) {
        if (threadIdx.x == 0) *flag = f;
        for (int idx = threadIdx.x; idx < 4128; idx += 256) {
            float v;
            if (f) {
                if (idx < 3072)      v = ((const float*)b_in)[idx];
                else if (idx < 4096) v = ((const float*)out_b)[idx - 3072];
                else if (idx < 4112) v = expf(fminf(((const float*)ls)[idx - 4096], LOGIT_MAX));
                else                 v = ((const float*)hs)[idx - 4112];
            } else {
                if (idx < 3072)      v = __bfloat162float(((const bf16*)b_in)[idx]);
                else if (idx < 4096) v = __bfloat162float(((const bf16*)out_b)[idx - 3072]);
                else if (idx < 4112) v = expf(fminf(__bfloat162float(((const bf16*)ls)[idx - 4096]), LOGIT_MAX));
                else                 v = __bfloat162float(((const bf16*)hs)[idx - 4112]);
            }
            smallf[idx] = v;
        }
    }
    if (f != 1) return;
    const size_t NX = 8388608, NW = 3145728, NO = 1048576;
    const size_t t0   = ((size_t)blockIdx.x * 256 + threadIdx.x) * 4;
    const size_t step = (size_t)gridDim.x * 256 * 4;
    for (size_t i = t0; i < NX; i += step) store4bf(xb + i, load4((const float*)x + i));
    for (size_t i = t0; i < NW; i += step) store4bf(wb + i, load4((const float*)w_in + i));
    for (size_t i = t0; i < NO; i += step) store4bf(owb + i, load4((const float*)out_w + i));
}

// ---------------------------------------------------------------------------
// Kernel 1: MFMA QKV projection, BK=64, fused q/k L2-normalize (R9 form —
// async16 staging from bf16 sources only; measured 86 us).
// ---------------------------------------------------------------------------
__global__ __launch_bounds__(256, 4) void qkv_gemm_mfma_kernel(
    const int* __restrict__ flag,
    const bf16* __restrict__ Xws, const bf16* __restrict__ Wws,
    const bf16* __restrict__ Xdir, const bf16* __restrict__ Wdir,
    const float* __restrict__ bias_f,
    bf16* __restrict__ q, bf16* __restrict__ k, bf16* __restrict__ vt)
{
    const bf16* X = (*flag) ? Xws : Xdir;
    const bf16* W = (*flag) ? Wws : Wdir;
    __shared__ bf16 A_lds[128 * 64];
    __shared__ bf16 B_lds[128 * 64];
    const int tid  = threadIdx.x;
    const int w    = tid >> 6;
    const int lane = tid & 63;
    const int l16  = lane & 15, quad = lane >> 4;
    const int wm   = w >> 1, wn = w & 1;
    const int row0 = blockIdx.y * 128;
    const int col0 = blockIdx.x * 128;
    const int sr   = lane >> 3, sc = lane & 7;
    const int scg  = sc ^ sr;            // source chunk for swizzled staging

    f32x4 acc[4][4] = {};

    for (int kt = 0; kt < 1024; kt += 64) {
        __syncthreads();
#pragma unroll
        for (int i = 0; i < 4; i++) {
            const int br = w * 32 + i * 8;     // 8 rows per inst, br % 8 == 0
            async16(X + (size_t)(row0 + br + sr) * 1024 + kt + scg * 8, &A_lds[br * 64]);
            async16(W + (size_t)(col0 + br + sr) * 1024 + kt + scg * 8, &B_lds[br * 64]);
        }
        __syncthreads();

#pragma unroll
        for (int kh = 0; kh < 2; kh++) {
            bf16x8 af[4], bf[4];
#pragma unroll
            for (int mt = 0; mt < 4; mt++) {
                const int row = wm * 64 + mt * 16 + l16;
                af[mt] = *(const bf16x8*)&A_lds[row * 64 + (((quad + kh * 4) ^ (row & 7)) * 8)];
            }
#pragma unroll
            for (int nt = 0; nt < 4; nt++) {
                const int row = wn * 64 + nt * 16 + l16;
                bf[nt] = *(const bf16x8*)&B_lds[row * 64 + (((quad + kh * 4) ^ (row & 7)) * 8)];
            }
#pragma unroll
            for (int mt = 0; mt < 4; mt++)
#pragma unroll
                for (int nt = 0; nt < 4; nt++)
                    acc[mt][nt] = __builtin_amdgcn_mfma_f32_16x16x32_bf16(af[mt], bf[nt], acc[mt][nt], 0, 0, 0);
        }
    }

    const int cbase = col0 + wn * 64;          // wave-uniform
    const int part  = cbase >> 10;
    const int h     = (cbase & 1023) >> 6;
    float bias[4];
#pragma unroll
    for (int nt = 0; nt < 4; nt++) bias[nt] = bias_f[cbase + nt * 16 + l16];

    if (part < 2) {
        bf16* dst0 = (part == 0) ? q : k;
#pragma unroll
        for (int mt = 0; mt < 4; mt++) {
#pragma unroll
            for (int rg = 0; rg < 4; rg++) {
                const int r = row0 + wm * 64 + mt * 16 + quad * 4 + rg;
                const int l = r >> 3, nn = r & 7;
                float val[4]; float ss = 0.f;
#pragma unroll
                for (int nt = 0; nt < 4; nt++) {
                    val[nt] = acc[mt][nt][rg] + bias[nt];
                    ss += val[nt] * val[nt];
                }
                ss += __shfl_xor(ss, 1); ss += __shfl_xor(ss, 2);
                ss += __shfl_xor(ss, 4); ss += __shfl_xor(ss, 8);
                const float inv = 1.f / fmaxf(sqrtf(ss), 1e-12f);
                bf16* dp = dst0 + ((size_t)((nn * 16 + h) * 1024 + l)) * 64;
#pragma unroll
                for (int nt = 0; nt < 4; nt++)
                    dp[nt * 16 + l16] = __float2bfloat16(val[nt] * inv);
            }
        }
    } else {
#pragma unroll
        for (int mt = 0; mt < 4; mt++) {
#pragma unroll
            for (int rg = 0; rg < 4; rg++) {
                const int r = row0 + wm * 64 + mt * 16 + quad * 4 + rg;
                const int l = r >> 3, nn = r & 7;
#pragma unroll
                for (int nt = 0; nt < 4; nt++) {
                    const int d = nt * 16 + l16;
                    vt[((size_t)((nn * 16 + h) * 64 + d)) * 1024 + l] =
                        __float2bfloat16(acc[mt][nt][rg] + bias[nt]);
                }
            }
        }
    }
}

// ---------------------------------------------------------------------------
// Kernel 3: MFMA flash attention v3 — 64 q-rows per wave (256/block),
// grid = 4 qt x 128 nh = 512 blocks (exactly 2/CU, single pass, no tail).
// K-fragments loaded once into registers per tile and reused across all 4
// row-groups (u); same for P-fragments; V-fragments reused 4x.
// DS ops/tile: 44 per 64 rows (vs v2's 56). Fixed-max softmax as before.
// ---------------------------------------------------------------------------
__global__ __launch_bounds__(256, 2) void attn_mfma_kernel(
    const bf16* __restrict__ q, const bf16* __restrict__ k,
    const bf16* __restrict__ vt, const float* __restrict__ scale_f,
    bf16* __restrict__ o)
{
    __shared__ bf16 K_lds[64][64];     // [key][d], swizzled chunks
    __shared__ bf16 Vt_lds[64][64];    // [d][key], swizzled chunks
    __shared__ bf16 P_lds[4][64][72];  // wave-private [qrow][key]
    __shared__ float l_lds[4][64];

    const int bid  = blockIdx.x;
    const int qt   = bid >> 7;         // 0..3 (256 q-rows each)
    const int nh   = bid & 127;        // fast index -> XCD = nh & 7
    const int h    = nh & 15;
    const int n    = nh >> 4;
    const int tid  = threadIdx.x;
    const int w    = tid >> 6;
    const int lane = tid & 63;
    const int l16  = lane & 15;
    const int quad = lane >> 4;

    const size_t base = (size_t)nh * (1024 * 64);
    const float ls   = scale_f[4096 + h];
    const float hs   = scale_f[4112 + h];
    const float lsl2 = ls * 1.4426950408889634f;

    // Q B-frags (persist): qrows qt*256 + w*64 + u*16 + l16
    bf16x8 qf[4][2];
#pragma unroll
    for (int u = 0; u < 4; u++) {
        const int qrow = qt * 256 + w * 64 + u * 16 + l16;
        const bf16* qp = q + base + (size_t)qrow * 64 + quad * 8;
        qf[u][0] = *(const bf16x8*)qp;
        qf[u][1] = *(const bf16x8*)(qp + 32);
    }

    f32x4 o_acc[4][4] = {};            // [u][d-subtile]
    float l_part[4] = {};

    const int sr = lane >> 3;
    const int sc = lane & 7;

    for (int j0 = 0; j0 < 1024; j0 += 64) {
        __syncthreads();
#pragma unroll
        for (int half = 0; half < 2; half++) {
            const int br  = w * 16 + half * 8;
            const int row = br + sr;
            const int cg  = sc ^ (row & 7);
            async16(k  + base + (size_t)(j0 + row) * 64 + cg * 8, &K_lds[br][0]);
            async16(vt + base + (size_t)row * 1024 + j0 + cg * 8, &Vt_lds[br][0]);
        }
        __syncthreads();

        // K-frags for the whole tile, read once, reused by all 4 u
        bf16x8 kf[4][2];
#pragma unroll
        for (int s = 0; s < 4; s++) {
            const int krow = s * 16 + l16;
            const int swz  = krow & 7;
            kf[s][0] = *(const bf16x8*)&K_lds[krow][(quad ^ swz) * 8];
            kf[s][1] = *(const bf16x8*)&K_lds[krow][((quad + 4) ^ swz) * 8];
        }

        // per row-group: S^T = K.Q^T, fixed-max softmax, P write
#pragma unroll
        for (int u = 0; u < 4; u++) {
#pragma unroll
            for (int s = 0; s < 4; s++) {
                f32x4 a = {};
                a = __builtin_amdgcn_mfma_f32_16x16x32_bf16(kf[s][0], qf[u][0], a, 0, 0, 0);
                a = __builtin_amdgcn_mfma_f32_16x16x32_bf16(kf[s][1], qf[u][1], a, 0, 0, 0);
                union { bf16 b[4]; uint2 uu; } pk;
                float sum = 0.f;
#pragma unroll
                for (int r = 0; r < 4; r++) {
                    const float p = exp2f(fmaf(a[r], lsl2, -lsl2));
                    pk.b[r] = __float2bfloat16(p);
                    sum += p;
                }
                l_part[u] += sum;
                *(uint2*)&P_lds[w][u * 16 + l16][s * 16 + quad * 4] = pk.uu;
            }
        }

        // P A-frags (wave-private LDS, no barrier needed)
        bf16x8 pf[4][2];
#pragma unroll
        for (int u = 0; u < 4; u++) {
            pf[u][0] = *(const bf16x8*)&P_lds[w][u * 16 + l16][quad * 8];
            pf[u][1] = *(const bf16x8*)&P_lds[w][u * 16 + l16][32 + quad * 8];
        }
        // PV: V-frags read once per d-subtile, reused by all 4 u
#pragma unroll
        for (int ds = 0; ds < 4; ds++) {
            const int vrow = ds * 16 + l16;
            const int swz  = vrow & 7;
            const bf16x8 vf0 = *(const bf16x8*)&Vt_lds[vrow][(quad ^ swz) * 8];
            const bf16x8 vf1 = *(const bf16x8*)&Vt_lds[vrow][((quad + 4) ^ swz) * 8];
#pragma unroll
            for (int u = 0; u < 4; u++) {
                o_acc[u][ds] = __builtin_amdgcn_mfma_f32_16x16x32_bf16(pf[u][0], vf0, o_acc[u][ds], 0, 0, 0);
                o_acc[u][ds] = __builtin_amdgcn_mfma_f32_16x16x32_bf16(pf[u][1], vf1, o_acc[u][ds], 0, 0, 0);
            }
        }
    }

    // final l reduction (lanes sharing l16 across quads hold partials)
#pragma unroll
    for (int u = 0; u < 4; u++) {
        float v = l_part[u];
        v += __shfl_xor(v, 16);
        v += __shfl_xor(v, 32);
        l_lds[w][u * 16 + l16] = v;
    }

    // epilogue: o_acc rows = quad*4+r, col = l16 (d-sub)
#pragma unroll
    for (int u = 0; u < 4; u++) {
#pragma unroll
        for (int r = 0; r < 4; r++) {
            const float inv = hs / l_lds[w][u * 16 + quad * 4 + r];
            const int row_l = qt * 256 + w * 64 + u * 16 + quad * 4 + r;
            bf16* dst = o + ((size_t)row_l * 8 + n) * 1024 + h * 64 + l16;
#pragma unroll
            for (int ds = 0; ds < 4; ds++)
                dst[ds * 16] = __float2bfloat16(o_acc[u][ds][r] * inv);
        }
    }
}

// ---------------------------------------------------------------------------
// Kernel 4: MFMA out projection, BK=64, single launch (runtime output dtype).
// ---------------------------------------------------------------------------
__global__ __launch_bounds__(256, 4) void out_gemm_mfma_kernel(
    const int* __restrict__ flag,
    const bf16* __restrict__ A,
    const bf16* __restrict__ Bws, const bf16* __restrict__ Bdir,
    const float* __restrict__ bias_f,
    float* __restrict__ outf, bf16* __restrict__ outb)
{
    const int f = *flag;
    const bf16* B = f ? Bws : Bdir;
    __shared__ bf16 A_lds[128 * 64];
    __shared__ bf16 B_lds[128 * 64];
    const int tid  = threadIdx.x;
    const int w    = tid >> 6;
    const int lane = tid & 63;
    const int l16  = lane & 15, quad = lane >> 4;
    const int wm   = w >> 1, wn = w & 1;
    const int row0 = blockIdx.y * 128;
    const int col0 = blockIdx.x * 128;
    const int sr   = lane >> 3, sc = lane & 7;
    const int scg  = sc ^ sr;

    f32x4 acc[4][4] = {};

    for (int kt = 0; kt < 1024; kt += 64) {
        __syncthreads();
#pragma unroll
        for (int i = 0; i < 4; i++) {
            const int br = w * 32 + i * 8;
            async16(A + (size_t)(row0 + br + sr) * 1024 + kt + scg * 8, &A_lds[br * 64]);
            async16(B + (size_t)(col0 + br + sr) * 1024 + kt + scg * 8, &B_lds[br * 64]);
        }
        __syncthreads();

#pragma unroll
        for (int kh = 0; kh < 2; kh++) {
            bf16x8 af[4], bf[4];
#pragma unroll
            for (int mt = 0; mt < 4; mt++) {
                const int row = wm * 64 + mt * 16 + l16;
                af[mt] = *(const bf16x8*)&A_lds[row * 64 + (((quad + kh * 4) ^ (row & 7)) * 8)];
            }
#pragma unroll
            for (int nt = 0; nt < 4; nt++) {
                const int row = wn * 64 + nt * 16 + l16;
                bf[nt] = *(const bf16x8*)&B_lds[row * 64 + (((quad + kh * 4) ^ (row & 7)) * 8)];
            }
#pragma unroll
            for (int mt = 0; mt < 4; mt++)
#pragma unroll
                for (int nt = 0; nt < 4; nt++)
                    acc[mt][nt] = __builtin_amdgcn_mfma_f32_16x16x32_bf16(af[mt], bf[nt], acc[mt][nt], 0, 0, 0);
        }
    }

#pragma unroll
    for (int mt = 0; mt < 4; mt++) {
        const int rbase = row0 + wm * 64 + mt * 16 + quad * 4;
#pragma unroll
        for (int nt = 0; nt < 4; nt++) {
            const int c = col0 + wn * 64 + nt * 16 + l16;
            const float bias = bias_f[c];
#pragma unroll
            for (int rg = 0; rg < 4; rg++) {
                const float v = acc[mt][nt][rg] + bias;
                const size_t idx = (size_t)(rbase + rg) * 1024 + c;
                if (f) outf[idx] = v; else outb[idx] = __float2bfloat16(v);
            }
        }
    }
}

// ---------------------------------------------------------------------------
extern "C" void kernel_launch(void* const* d_in, const int* in_sizes, int n_in,
                              void* d_out, int out_size, void* d_ws, size_t ws_size,
                              hipStream_t stream)
{
    const size_t SEG = (size_t)8 * 16 * 1024 * 64;   // 8388608 elems
    bf16* qn  = (bf16*)d_ws;
    bf16* kn  = qn + SEG;
    bf16* vt  = kn + SEG;
    bf16* ow  = vt + SEG;
    bf16* xb  = ow + SEG;                  // bf16 copy of x (fp32 mode)
    bf16* wb  = xb + SEG;                  // bf16 copy of in_proj_weight
    bf16* owb = wb + 3145728;              // bf16 copy of out_w
    float* smallf = (float*)(owb + 1048576);   // 4128 floats
    int*   flag   = (int*)(smallf + 4128);

    // 0) prep (self-detecting dtype; flag + smallf; bf16 copies incl. x)
    prep_kernel<<<2048, 256, 0, stream>>>(
        d_in[0], d_in[1], d_in[5], d_in[2], d_in[6], d_in[3], d_in[4],
        xb, wb, owb, smallf, flag);

    // 1) qkv projection (MFMA, BK=64) + fused q/k L2-normalize
    qkv_gemm_mfma_kernel<<<dim3(3072 / 128, 8192 / 128), 256, 0, stream>>>(
        flag, xb, wb, (const bf16*)d_in[0], (const bf16*)d_in[1], smallf, qn, kn, vt);

    // 2) flash attention v3 (64 rows/wave, grid 512, XCD-local nh)
    attn_mfma_kernel<<<dim3(128 * 4), 256, 0, stream>>>(qn, kn, vt, smallf, ow);

    // 3) out projection (MFMA, BK=64), single launch
    out_gemm_mfma_kernel<<<dim3(1024 / 128, 8192 / 128), 256, 0, stream>>>(
        flag, ow, owb, (const bf16*)d_in[5], smallf + 3072,
        (float*)d_out, (bf16*)d_out);
}